// Round 1
// baseline (658.165 us; speedup 1.0000x reference)
//
#include <hip/hip_runtime.h>

// S_LSTM: T=16 timesteps, H=1024, NLAYER=4.
// Key insight: all reference ops are elementwise/broadcast over (H,H) --
// element (r,c) of every (t, layer) depends only on element (r,c) elsewhere.
// => 1M independent scalar LSTM chains; one thread per (r,c), state+weights
// in registers across the whole time loop. No syncs needed anywhere.

constexpr int T  = 16;
constexpr int H  = 1024;
constexpr int NL = 4;
constexpr int HH = H * H;

__device__ __forceinline__ float sigmoid_f(float z) {
    // 1/(1+e^-z); v_exp + v_rcp (approx rcp is plenty for 2% tolerance)
    return __builtin_amdgcn_rcpf(1.0f + __expf(-z));
}
__device__ __forceinline__ float tanh_f(float z) {
    // tanh(z) = 2*sigmoid(2z) - 1; saturates correctly at +-1 via exp->0/inf
    return fmaf(2.0f, sigmoid_f(2.0f * z), -1.0f);
}

__global__ __launch_bounds__(256)
void slstm_kernel(const float* __restrict__ x,
                  const float* __restrict__ Wxi, const float* __restrict__ Wxf,
                  const float* __restrict__ Wxc, const float* __restrict__ Wxo,
                  const float* __restrict__ Whi, const float* __restrict__ Whf,
                  const float* __restrict__ Whc, const float* __restrict__ Who,
                  const float* __restrict__ Whsi, const float* __restrict__ Whsf,
                  const float* __restrict__ Whsc, const float* __restrict__ Whso,
                  const float* __restrict__ bi, const float* __restrict__ bf,
                  const float* __restrict__ bc, const float* __restrict__ bo,
                  float* __restrict__ out)
{
    const int idx = blockIdx.x * blockDim.x + threadIdx.x;   // 0 .. HH-1
    const int r = idx >> 10;          // row    (x broadcast index)
    const int c = idx & (H - 1);      // column (Wx/b broadcast index)

    // ---- load all per-position weights into registers (reused 16x) ----
    float whi[NL], whf[NL], whc[NL], who[NL];
    float wxi[NL], wxf[NL], wxc[NL], wxo[NL];
    float vbi[NL], vbf[NL], vbc[NL], vbo[NL];
#pragma unroll
    for (int i = 0; i < NL; ++i) {
        whi[i] = Whi[i * HH + idx];
        whf[i] = Whf[i * HH + idx];
        whc[i] = Whc[i * HH + idx];
        who[i] = Who[i * HH + idx];
        wxi[i] = Wxi[i * H + c];
        wxf[i] = Wxf[i * H + c];
        wxc[i] = Wxc[i * H + c];
        wxo[i] = Wxo[i * H + c];
        vbi[i] = bi[i * H + c];
        vbf[i] = bf[i * H + c];
        vbc[i] = bc[i * H + c];
        vbo[i] = bo[i * H + c];
    }
    float wsi[NL - 1], wsf[NL - 1], wsc[NL - 1], wso[NL - 1];
#pragma unroll
    for (int j = 0; j < NL - 1; ++j) {
        wsi[j] = Whsi[j * HH + idx];
        wsf[j] = Whsf[j * HH + idx];
        wsc[j] = Whsc[j * HH + idx];
        wso[j] = Whso[j * HH + idx];
    }

    float cs[NL] = {0.f, 0.f, 0.f, 0.f};
    float hs[NL] = {0.f, 0.f, 0.f, 0.f};

    for (int t = 0; t < T; ++t) {
        const float xv = x[t * H + r];                 // wave-uniform broadcast
        float* outp = out + (size_t)t * (2 * NL * HH) + idx;
        float hbelow = 0.0f;
#pragma unroll
        for (int i = 0; i < NL; ++i) {
            float zi = fmaf(xv, wxi[i], fmaf(hs[i], whi[i], vbi[i]));
            float zf = fmaf(xv, wxf[i], fmaf(hs[i], whf[i], vbf[i]));
            float zc = fmaf(xv, wxc[i], fmaf(hs[i], whc[i], vbc[i]));
            float zo = fmaf(xv, wxo[i], fmaf(hs[i], who[i], vbo[i]));
            if (i > 0) {   // layer-skip from h of layer below (this timestep)
                zi = fmaf(hbelow, wsi[i - 1], zi);
                zf = fmaf(hbelow, wsf[i - 1], zf);
                zc = fmaf(hbelow, wsc[i - 1], zc);
                zo = fmaf(hbelow, wso[i - 1], zo);
            }
            const float ig = sigmoid_f(zi);
            const float fg = sigmoid_f(zf);
            const float og = sigmoid_f(zo);
            const float cc = tanh_f(zc);
            const float cn = fmaf(fg, cs[i], ig * cc);
            const float hn = og * tanh_f(cn);
            cs[i] = cn;
            hs[i] = hn;
            hbelow = hn;
            // ys layout: (T, 2, NL, H, H) -- c plane then h plane
            outp[(size_t)i * HH]        = cn;
            outp[(size_t)(NL + i) * HH] = hn;
        }
    }
}

extern "C" void kernel_launch(void* const* d_in, const int* in_sizes, int n_in,
                              void* d_out, int out_size, void* d_ws, size_t ws_size,
                              hipStream_t stream) {
    const float* x    = (const float*)d_in[0];
    const float* Wxi  = (const float*)d_in[1];
    const float* Wxf  = (const float*)d_in[2];
    const float* Wxc  = (const float*)d_in[3];
    const float* Wxo  = (const float*)d_in[4];
    const float* Whi  = (const float*)d_in[5];
    const float* Whf  = (const float*)d_in[6];
    const float* Whc  = (const float*)d_in[7];
    const float* Who  = (const float*)d_in[8];
    const float* Whsi = (const float*)d_in[9];
    const float* Whsf = (const float*)d_in[10];
    const float* Whsc = (const float*)d_in[11];
    const float* Whso = (const float*)d_in[12];
    const float* bi   = (const float*)d_in[13];
    const float* bf   = (const float*)d_in[14];
    const float* bc   = (const float*)d_in[15];
    const float* bo   = (const float*)d_in[16];
    float* out = (float*)d_out;

    dim3 grid(HH / 256), block(256);
    slstm_kernel<<<grid, block, 0, stream>>>(x, Wxi, Wxf, Wxc, Wxo,
                                             Whi, Whf, Whc, Who,
                                             Whsi, Whsf, Whsc, Whso,
                                             bi, bf, bc, bo, out);
}